// Round 4
// baseline (278.041 us; speedup 1.0000x reference)
//
#include <hip/hip_runtime.h>
#include <hip/hip_bf16.h>

// GVPDynamicProjection: N=10000, C=2, SI=128, VI=16, H=4, R=32, SH=32, VH=4
// R17 = R16 with kA's broadcast LDS reads moved to the scalar pipe.
// Theory (from R16 counters): kA was DS-pipe-bound: 288 broadcast
// ds_read_b128/wave in 2a (~39 us/CU at 12cyc each) with VALU only 28% busy.
// Fix: x operands in 2a/2b are wave-uniform -> each wave owns a row-set
// (rw0 via readfirstlane) and reads x straight from global s with uniform
// addresses (compiler scalarizes to s_load_dwordx4 -> SMEM pipe, not DS).
// XT staging deleted; vn kept in a tiny VN[2][16][16] LDS array (32 b128/wave).
// SO buffer + phase 4 deleted: eq computed by a 5-step __shfl_xor butterfly
// over each 32-lane col group from silu registers. LDS 31.2->20KB.
// kAccum / kSmall / kAttn byte-identical to R13/R16.

#define N_  10000
#define C_  2
#define SI_ 128
#define VI_ 16
#define H_  4
#define R_  32
#define SH_ 32
#define VH_ 4
#define NC_ (N_*C_)

#define ROWS_ 16

typedef const float* __restrict__ fptr;

__device__ __forceinline__ float sigm(float x){ return 1.f/(1.f+__expf(-x)); }

// ---------------- ws layout (float offsets) ----------------
// pexp : [C_*32][N_]   exp(logits), TRANSPOSED      640000
// eqh  : [NC_][100]    per-row eq[4] @0, qh[96] @8  2000000
// sg   : [64][180]     sums: d<176 = sum e^l*x, 176 = sum e^l (zeroed by kA blk0)
// tkh/tek/tvs/tvv: attn tables
#define OFF_LG   0
#define OFF_EQH  640000
#define OFF_SG   2640000
#define OFF_TKH  2651520
#define OFF_TEK  2657664
#define OFF_TVS  2657920
#define OFF_TVV  2666112

#define SGSTRIDE_ 180

// ================= kernel A: per-row logits + q-path =================
// 256 threads, 16 rows/block; grid = NC_/16 = 1250; ~20KB LDS -> 8 blk/CU cap
__global__ __launch_bounds__(256) void kA(
    fptr s, fptr v,
    fptr wp_wh, fptr wp_ws_w, fptr wp_ws_b,
    fptr q_wh, fptr q_ws_w, fptr q_ws_b, fptr q_wv, fptr q_wsv_w, fptr q_wsv_b,
    fptr attn_wh, fptr attn_ws_w,
    float* __restrict__ pexp, float* __restrict__ eqh,
    float* __restrict__ sgz)
{
  __shared__ __align__(16) float SIG[ROWS_*128];   // 8KB  (sigmoid(so))
  __shared__ __align__(16) float VN[2][16*16];     // 2KB  [path][i][row]
  __shared__ __align__(16) float VVs[ROWS_*48];    // 3KB
  __shared__ __align__(16) float VHQ[ROWS_*48];    // 3KB
  __shared__ __align__(16) float GATE[ROWS_*16];   // 1KB
  __shared__ __align__(16) float QV[ROWS_*48];     // 3KB

  const int tid  = threadIdx.x;
  const int lane = tid & 63;
  const int wv   = __builtin_amdgcn_readfirstlane(tid >> 6);  // wave id 0..3
  const int row0 = blockIdx.x * ROWS_;

  // block 0 also zeroes sg (kAccum is stream-ordered after all kA blocks)
  if (blockIdx.x == 0){
    for (int i = tid; i < 64*SGSTRIDE_; i += 256) sgz[i] = 0.f;
  }

  // phase 0: stage v only (s is now read via the scalar path in 2a/2b)
  for (int idx = tid; idx < ROWS_*48; idx += 256){
    int r = idx / 48, k = idx - r*48;
    VVs[r*48 + k] = v[(row0+r)*48 + k];
  }
  __syncthreads();

  // phase 1: vh / vn, 16 rows x 32 (path,i) = 512 work items
  for (int idx = tid; idx < ROWS_*32; idx += 256){
    int r = idx >> 5, ii = idx & 31, path = ii >> 4, i = ii & 15;
    fptr wh = path ? wp_wh : q_wh;
    float h0=0.f, h1=0.f, h2=0.f;
    #pragma unroll
    for (int j = 0; j < 16; j++){
      float w = wh[j*16 + i];
      h0 = fmaf(VVs[r*48 + j*3 + 0], w, h0);
      h1 = fmaf(VVs[r*48 + j*3 + 1], w, h1);
      h2 = fmaf(VVs[r*48 + j*3 + 2], w, h2);
    }
    float vn = sqrtf(fmaxf(h0*h0 + h1*h1 + h2*h2, 1e-8f));
    if (!path){
      VHQ[r*48 +  0 + i] = h0;
      VHQ[r*48 + 16 + i] = h1;
      VHQ[r*48 + 32 + i] = h2;
      VN[0][i*16 + r] = vn;
    } else {
      VN[1][i*16 + r] = vn;
    }
  }
  __syncthreads();

  // phase 2a: so = [s, vn_q] @ q_ws_w + b
  // wave wv: cols (wv&1)*64 + lane, rows (wv>>1)*8 .. +7 (acc[8]).
  // x reads are wave-uniform -> scalar loads (SMEM), zero DS traffic.
  const int col = (wv & 1)*64 + lane;
  const int rw0 = (wv >> 1)*8;
  const float* __restrict__ srow = s + (size_t)(row0 + rw0)*128;  // uniform
  float acc[8];
  {
    float bqs = q_ws_b[col];
    #pragma unroll
    for (int k = 0; k < 8; k++) acc[k] = bqs;
    #pragma unroll 2
    for (int jb = 0; jb < 128; jb += 4){
      float w0 = q_ws_w[(jb+0)*128 + col];     // coalesced 64-consec/wave
      float w1 = q_ws_w[(jb+1)*128 + col];
      float w2 = q_ws_w[(jb+2)*128 + col];
      float w3 = q_ws_w[(jb+3)*128 + col];
      #pragma unroll
      for (int k = 0; k < 8; k++){
        float4 x = *(const float4*)(srow + k*128 + jb);  // uniform -> s_load
        acc[k] = fmaf(x.x, w0, acc[k]);
        acc[k] = fmaf(x.y, w1, acc[k]);
        acc[k] = fmaf(x.z, w2, acc[k]);
        acc[k] = fmaf(x.w, w3, acc[k]);
      }
    }
    // vn_q part (j = 128..143) from LDS: 32 b128 per wave total
    #pragma unroll
    for (int i = 0; i < 16; i++){
      float w = q_ws_w[(128+i)*128 + col];
      float4 xa = *(const float4*)&VN[0][i*16 + rw0];
      float4 xb = *(const float4*)&VN[0][i*16 + rw0 + 4];
      acc[0] = fmaf(xa.x, w, acc[0]); acc[1] = fmaf(xa.y, w, acc[1]);
      acc[2] = fmaf(xa.z, w, acc[2]); acc[3] = fmaf(xa.w, w, acc[3]);
      acc[4] = fmaf(xb.x, w, acc[4]); acc[5] = fmaf(xb.y, w, acc[5]);
      acc[6] = fmaf(xb.z, w, acc[6]); acc[7] = fmaf(xb.w, w, acc[7]);
    }
  }

  // phase 2b: logits -> exp, transposed store. wave wv handles rows wv*4..+3;
  // lanes 32-63 replicate lanes 0-31 (same SIMD issue, zero extra cycles).
  {
    const int colB = lane & 31;
    const int rw0b = wv*4;
    const float* __restrict__ srb = s + (size_t)(row0 + rw0b)*128;  // uniform
    float bb = wp_ws_b[colB];
    float b4[4];
    #pragma unroll
    for (int k = 0; k < 4; k++) b4[k] = bb;
    #pragma unroll 2
    for (int jb = 0; jb < 128; jb += 4){
      float w0 = wp_ws_w[(jb+0)*32 + colB];
      float w1 = wp_ws_w[(jb+1)*32 + colB];
      float w2 = wp_ws_w[(jb+2)*32 + colB];
      float w3 = wp_ws_w[(jb+3)*32 + colB];
      #pragma unroll
      for (int k = 0; k < 4; k++){
        float4 x = *(const float4*)(srb + k*128 + jb);   // uniform -> s_load
        b4[k] = fmaf(x.x, w0, b4[k]);
        b4[k] = fmaf(x.y, w1, b4[k]);
        b4[k] = fmaf(x.z, w2, b4[k]);
        b4[k] = fmaf(x.w, w3, b4[k]);
      }
    }
    #pragma unroll
    for (int i = 0; i < 16; i++){
      float w = wp_ws_w[(128+i)*32 + colB];
      float4 xv = *(const float4*)&VN[1][i*16 + rw0b];   // 4 rows, one b128
      b4[0] = fmaf(xv.x, w, b4[0]);
      b4[1] = fmaf(xv.y, w, b4[1]);
      b4[2] = fmaf(xv.z, w, b4[2]);
      b4[3] = fmaf(xv.w, w, b4[3]);
    }
    if (lane < 32){
      #pragma unroll
      for (int k = 0; k < 4; k++){
        const int gr = row0 + rw0b + k;                  // global row
        pexp[((gr & 1)*32 + colB)*N_ + (gr >> 1)] = __expf(b4[k]);
      }
    }
  }

  // phase 2c: sigmoid -> SIG (for gate); silu -> eq via 32-lane butterfly
  {
    const float weq = attn_ws_w[col & 31];
    float e[8];
    #pragma unroll
    for (int k = 0; k < 8; k++){
      float so  = acc[k];
      float sg_ = sigm(so);
      SIG[(rw0 + k)*128 + col] = sg_;
      e[k] = so * sg_ * weq;                 // silu * ws_q[col&31]
    }
    #pragma unroll
    for (int m = 1; m <= 16; m <<= 1){
      #pragma unroll
      for (int k = 0; k < 8; k++)
        e[k] += __shfl_xor(e[k], m, 64);     // reduces within 32-lane group
    }
    if ((lane & 31) == 0){
      const int h = col >> 5;
      #pragma unroll
      for (int k = 0; k < 8; k++)
        eqh[(row0 + rw0 + k)*100 + h] = e[k];
    }
  }
  __syncthreads();

  // phase 3: gate = sigmoid(sig_so @ q_wsv_w + b)  (16 rows x 16 = 256 thr)
  {
    const int r = tid >> 4, g = tid & 15;
    float ga = q_wsv_b[g];
    #pragma unroll 8
    for (int o = 0; o < 128; o += 4){
      float4 s4 = *(const float4*)&SIG[r*128 + o];
      ga = fmaf(s4.x, q_wsv_w[(o+0)*16 + g], ga);
      ga = fmaf(s4.y, q_wsv_w[(o+1)*16 + g], ga);
      ga = fmaf(s4.z, q_wsv_w[(o+2)*16 + g], ga);
      ga = fmaf(s4.w, q_wsv_w[(o+3)*16 + g], ga);
    }
    GATE[r*16 + g] = sigm(ga);
  }
  __syncthreads();

  // phase 5: qv = (vh_q @ q_wv)^T * gate   (16*48 = 768 work items)
  for (int t = tid; t < ROWS_*48; t += 256){
    int r = t / 48, k = t - r*48, i = k / 3, d = k - i*3;
    float a = 0.f;
    #pragma unroll
    for (int j = 0; j < 16; j++)
      a = fmaf(VHQ[r*48 + d*16 + j], q_wv[j*16 + i], a);
    QV[r*48 + k] = a * GATE[r*16 + i];
  }
  __syncthreads();

  // phase 6: qh[h][d][e] = sum_i qv[h*4+i][d] * wh_q[i][e]  (16*96 = 1536)
  for (int t = tid; t < ROWS_*96; t += 256){
    int r = t / 96, k = t - r*96;
    int h = k / 24, rem = k - h*24, d = rem >> 3, ee = rem & 7;
    float a = 0.f;
    #pragma unroll
    for (int i = 0; i < 4; i++)
      a = fmaf(QV[r*48 + (h*4 + i)*3 + d], attn_wh[i*8 + ee], a);
    eqh[(row0 + r)*100 + 8 + k] = a;
  }
}

// ===== kAccum: weighted sums via atomics, 800 blocks = 3200 waves ==========
__global__ __launch_bounds__(256) void kAccum(const float* __restrict__ pexp,
                                              fptr s, fptr v,
                                              float* __restrict__ sg)
{
  const int b = blockIdx.x;
  const int c = b & 1, ah = (b >> 1) & 1, chunk = b >> 2;
  const int n0 = chunk * 50;
  const int tid = threadIdx.x;
  const int ag = tid >> 6, dl = tid & 63;
  const int abase = ah*16 + ag*4;

  const float* pb = pexp + (c*32 + abase)*N_;
  float acc[4][3] = {};
  float dn[4] = {};

  #pragma unroll 2
  for (int n = n0; n < n0 + 50; n++){
    const int rc = n*2 + c;
    float pw[4];
    #pragma unroll
    for (int aa = 0; aa < 4; aa++){
      pw[aa] = pb[aa*N_ + n];
      dn[aa] += pw[aa];
    }
    #pragma unroll
    for (int dd = 0; dd < 3; dd++){
      int d = dl + 64*dd;
      if (d < 176){
        float xv = (d < 128) ? s[rc*128 + d] : v[rc*48 + d - 128];
        #pragma unroll
        for (int aa = 0; aa < 4; aa++)
          acc[aa][dd] = fmaf(pw[aa], xv, acc[aa][dd]);
      }
    }
  }
  #pragma unroll
  for (int aa = 0; aa < 4; aa++){
    const int base = (c*32 + abase + aa)*SGSTRIDE_;
    #pragma unroll
    for (int dd = 0; dd < 3; dd++){
      int d = dl + 64*dd;
      if (d < 176) atomicAdd(&sg[base + d], acc[aa][dd]);
    }
    if (dl == 0) atomicAdd(&sg[base + 176], dn[aa]);
  }
}

// ================= kSmall: normalize + k/vv GVP + attn tables ===============
__global__ __launch_bounds__(256) void kSmall(
    const float* __restrict__ sg,
    fptr k_wh, fptr k_ws_w, fptr k_ws_b, fptr k_wv, fptr k_wsv_w, fptr k_wsv_b,
    fptr vv_wh, fptr vv_ws_w, fptr vv_ws_b, fptr vv_wv, fptr vv_wsv_w, fptr vv_wsv_b,
    fptr attn_wh, fptr attn_ws_w,
    float* __restrict__ tkh, float* __restrict__ tek,
    float* __restrict__ tvs, float* __restrict__ tvv)
{
  const int b = blockIdx.x, r = b >> 1, c = b & 1;
  const int tid = threadIdx.x;
  __shared__ float X[176];
  __shared__ float VN[2][16];
  __shared__ float VH[2][48];
  __shared__ float SOk[128], SOv[128];
  __shared__ float G[2][16];
  __shared__ float KV[48];

  if (tid < 176){
    const float* p = sg + (c*32 + r)*SGSTRIDE_;
    X[tid] = p[tid] / p[176];
  }
  __syncthreads();

  if (tid < 32){
    int path = tid >> 4, i = tid & 15;
    fptr wh = path ? vv_wh : k_wh;
    float h0=0.f, h1=0.f, h2=0.f;
    #pragma unroll
    for (int j = 0; j < 16; j++){
      float w = wh[j*16 + i];
      h0 = fmaf(X[128 + j*3 + 0], w, h0);
      h1 = fmaf(X[128 + j*3 + 1], w, h1);
      h2 = fmaf(X[128 + j*3 + 2], w, h2);
    }
    VH[path][ 0 + i] = h0; VH[path][16 + i] = h1; VH[path][32 + i] = h2;
    VN[path][i] = sqrtf(fmaxf(h0*h0 + h1*h1 + h2*h2, 1e-8f));
  }
  __syncthreads();

  {
    int path = tid >> 7, col = tid & 127;
    fptr W  = path ? vv_ws_w : k_ws_w;
    fptr Bb = path ? vv_ws_b : k_ws_b;
    float so = Bb[col];
    for (int j = 0; j < 128; j++) so = fmaf(X[j], W[j*128 + col], so);
    #pragma unroll
    for (int i = 0; i < 16; i++)  so = fmaf(VN[path][i], W[(128+i)*128 + col], so);
    (path ? SOv : SOk)[col] = so;
  }
  __syncthreads();

  if (tid < 32){
    int path = tid >> 4, g = tid & 15;
    fptr Wsv = path ? vv_wsv_w : k_wsv_w;
    fptr Bsv = path ? vv_wsv_b : k_wsv_b;
    const float* SOp = path ? SOv : SOk;
    float ga = Bsv[g];
    for (int o = 0; o < 128; o++)
      ga = fmaf(sigm(SOp[o]), Wsv[o*16 + g], ga);
    G[path][g] = sigm(ga);
  } else if (tid < 36){
    int h = tid - 32;
    float e = 0.f;
    #pragma unroll
    for (int t = 0; t < 32; t++){
      float so = SOk[h*32 + t];
      e = fmaf(so * sigm(so), attn_ws_w[32 + t], e);
    }
    tek[(r*2 + c)*4 + h] = e;
  } else if (tid >= 64 && tid < 192){
    int o = tid - 64;
    float so = SOv[o];
    tvs[(r*2 + c)*128 + o] = so * sigm(so);
  }
  __syncthreads();

  if (tid < 96){
    int path = tid / 48, k = tid % 48, i = k / 3, d = k - i*3;
    fptr Wv = path ? vv_wv : k_wv;
    float vo = 0.f;
    #pragma unroll
    for (int j = 0; j < 16; j++)
      vo = fmaf(VH[path][d*16 + j], Wv[j*16 + i], vo);
    float gv = vo * G[path][i];
    if (path == 0) KV[k] = gv;
    else {
      int h = i >> 2, ii = i & 3;
      tvv[(((r*2 + c)*4 + h)*4 + ii)*3 + d] = gv;
    }
  }
  __syncthreads();

  if (tid < 96){
    int h = tid / 24, rem = tid % 24, d = rem >> 3, ee = rem & 7;
    float a = 0.f;
    #pragma unroll
    for (int i = 0; i < 4; i++)
      a = fmaf(KV[(h*4 + i)*3 + d], attn_wh[(4 + i)*8 + ee], a);
    tkh[((r*2 + c)*4 + h)*24 + d*8 + ee] = a;
  }
}

// ================= kAttn (R9-measured): one row/thread ======================
__global__ __launch_bounds__(512, 1) void kAttn(
    const float* __restrict__ eqh,
    const float* __restrict__ tkh, const float* __restrict__ tek,
    const float* __restrict__ tvs, const float* __restrict__ tvv,
    fptr attn_ws_w, fptr attn_ws_b,
    float* __restrict__ out)
{
  __shared__ __align__(16) float KH[6144];
  __shared__ __align__(16) float EK[256];
  __shared__ __align__(16) float VS[256*36];
  __shared__ __align__(16) float VVt[3072];
  const int tid = threadIdx.x;

  for (int i = tid; i < 6144; i += 512) KH[i] = tkh[i];
  if (tid < 256) EK[tid] = tek[tid];
  for (int i = tid; i < 8192; i += 512){ int base = i >> 5, t = i & 31; VS[base*36 + t] = tvs[i]; }
  for (int i = tid; i < 3072; i += 512) VVt[i] = tvv[i];

  float wsn[8];
  #pragma unroll
  for (int ee = 0; ee < 8; ee++) wsn[ee] = attn_ws_w[64 + ee];
  const float wb = attn_ws_b[0];
  __syncthreads();

  const int row = blockIdx.x*128 + (tid >> 2);
  const int h = tid & 3;
  if (row < NC_){
    const int c = row & 1;
    const float eq = eqh[row*100 + h];
    float qh[24];
    {
      const float4* qp = (const float4*)&eqh[row*100 + 8 + h*24];
      #pragma unroll
      for (int k = 0; k < 6; k++){
        float4 t4 = qp[k];
        qh[k*4+0] = t4.x; qh[k*4+1] = t4.y; qh[k*4+2] = t4.z; qh[k*4+3] = t4.w;
      }
    }
    float4 accs4[8];
    float4 accv4[3];
    #pragma unroll
    for (int q = 0; q < 8; q++) accs4[q] = make_float4(0.f,0.f,0.f,0.f);
    #pragma unroll
    for (int q = 0; q < 3; q++) accv4[q] = make_float4(0.f,0.f,0.f,0.f);
    float den = 0.f;

    #pragma unroll
    for (int r = 0; r < 32; r++){
      const int base = (r*2 + c)*4 + h;
      const float* khp = &KH[base*24];
      float en = 0.f;
      #pragma unroll
      for (int ee = 0; ee < 8; ee++){
        float a0 = qh[ee]      + khp[ee];
        float a1 = qh[8 + ee]  + khp[8 + ee];
        float a2 = qh[16 + ee] + khp[16 + ee];
        en = fmaf(sqrtf(fmaxf(a0*a0 + a1*a1 + a2*a2, 1e-8f)), wsn[ee], en);
      }
      const float w = __expf((eq + EK[base] + en + wb) * 0.17677669529663687f);
      den += w;
      const float4* vp4 = (const float4*)&VS[base*36];
      #pragma unroll
      for (int q = 0; q < 8; q++){
        float4 t4 = vp4[q];
        accs4[q].x = fmaf(w, t4.x, accs4[q].x);
        accs4[q].y = fmaf(w, t4.y, accs4[q].y);
        accs4[q].z = fmaf(w, t4.z, accs4[q].z);
        accs4[q].w = fmaf(w, t4.w, accs4[q].w);
      }
      const float4* vv4 = (const float4*)&VVt[base*12];
      #pragma unroll
      for (int q = 0; q < 3; q++){
        float4 t4 = vv4[q];
        accv4[q].x = fmaf(w, t4.x, accv4[q].x);
        accv4[q].y = fmaf(w, t4.y, accv4[q].y);
        accv4[q].z = fmaf(w, t4.z, accv4[q].z);
        accv4[q].w = fmaf(w, t4.w, accv4[q].w);
      }
    }
    const float inv = 1.f / den;
    float4* po = (float4*)&out[row*128 + h*32];
    #pragma unroll
    for (int q = 0; q < 8; q++){
      float4 t4 = accs4[q];
      t4.x *= inv; t4.y *= inv; t4.z *= inv; t4.w *= inv;
      po[q] = t4;
    }
    float4* pv = (float4*)&out[NC_*128 + row*48 + h*12];
    #pragma unroll
    for (int q = 0; q < 3; q++){
      float4 t4 = accv4[q];
      t4.x *= inv; t4.y *= inv; t4.z *= inv; t4.w *= inv;
      pv[q] = t4;
    }
  }
}

extern "C" void kernel_launch(void* const* d_in, const int* in_sizes, int n_in,
                              void* d_out, int out_size, void* d_ws, size_t ws_size,
                              hipStream_t stream)
{
  fptr s        = (fptr)d_in[0];
  fptr v        = (fptr)d_in[1];
  fptr wp_wh    = (fptr)d_in[2];
  fptr wp_ws_w  = (fptr)d_in[3];
  fptr wp_ws_b  = (fptr)d_in[4];
  fptr q_wh     = (fptr)d_in[5];
  fptr q_ws_w   = (fptr)d_in[6];
  fptr q_ws_b   = (fptr)d_in[7];
  fptr q_wv     = (fptr)d_in[8];
  fptr q_wsv_w  = (fptr)d_in[9];
  fptr q_wsv_b  = (fptr)d_in[10];
  fptr k_wh     = (fptr)d_in[11];
  fptr k_ws_w   = (fptr)d_in[12];
  fptr k_ws_b   = (fptr)d_in[13];
  fptr k_wv     = (fptr)d_in[14];
  fptr k_wsv_w  = (fptr)d_in[15];
  fptr k_wsv_b  = (fptr)d_in[16];
  fptr vv_wh    = (fptr)d_in[17];
  fptr vv_ws_w  = (fptr)d_in[18];
  fptr vv_ws_b  = (fptr)d_in[19];
  fptr vv_wv    = (fptr)d_in[20];
  fptr vv_wsv_w = (fptr)d_in[21];
  fptr vv_wsv_b = (fptr)d_in[22];
  fptr attn_wh  = (fptr)d_in[23];
  fptr attn_ws_w= (fptr)d_in[24];
  fptr attn_ws_b= (fptr)d_in[25];

  float* ws   = (float*)d_ws;
  float* pexp = ws + OFF_LG;
  float* eqh  = ws + OFF_EQH;
  float* sg   = ws + OFF_SG;
  float* tkh  = ws + OFF_TKH;
  float* tek  = ws + OFF_TEK;
  float* tvs  = ws + OFF_TVS;
  float* tvv  = ws + OFF_TVV;

  kA<<<NC_/ROWS_, 256, 0, stream>>>(s, v, wp_wh, wp_ws_w, wp_ws_b,
                                    q_wh, q_ws_w, q_ws_b, q_wv, q_wsv_w, q_wsv_b,
                                    attn_wh, attn_ws_w, pexp, eqh, sg);
  kAccum<<<800, 256, 0, stream>>>(pexp, s, v, sg);
  kSmall<<<64, 256, 0, stream>>>(sg,
                                 k_wh, k_ws_w, k_ws_b, k_wv, k_wsv_w, k_wsv_b,
                                 vv_wh, vv_ws_w, vv_ws_b, vv_wv, vv_wsv_w, vv_wsv_b,
                                 attn_wh, attn_ws_w, tkh, tek, tvs, tvv);
  kAttn<<<(NC_ + 127)/128, 512, 0, stream>>>(eqh, tkh, tek, tvs, tvv,
                                             attn_ws_w, attn_ws_b, (float*)d_out);
}

// Round 5
// 250.285 us; speedup vs baseline: 1.1109x; 1.1109x over previous
//
#include <hip/hip_runtime.h>
#include <hip/hip_bf16.h>

// GVPDynamicProjection: N=10000, C=2, SI=128, VI=16, H=4, R=32, SH=32, VH=4
// R18 = R16 reverted (R17's scalar-x path regressed: VGPR 124, FETCH +5MB,
// occupancy 17%) with kA split into TWO half-grid dispatches (row_base 0 and
// 10000). DIAGNOSTIC round: total ~= kA + ~192us constant across R13-R17;
// every non-kA kernel hides below the top-5 cutoff. Halving kA's dispatch
// duration (~24us each) forces kAccum/kSmall/kAttn into the top-5 with full
// counters, separating "hidden slow kernel (atomics?)" from "fixed graph
// overhead floor". kA inner code byte-identical to R16 (47us, best known).
// kAccum / kSmall / kAttn byte-identical to R13/R16.

#define N_  10000
#define C_  2
#define SI_ 128
#define VI_ 16
#define H_  4
#define R_  32
#define SH_ 32
#define VH_ 4
#define NC_ (N_*C_)

#define ROWS_ 16
#define XSTR_ 20   // XT leading stride: 16 rows + 4 pad; 80B = 5x16B aligned

typedef const float* __restrict__ fptr;

__device__ __forceinline__ float sigm(float x){ return 1.f/(1.f+__expf(-x)); }

// ---------------- ws layout (float offsets) ----------------
// pexp : [C_*32][N_]   exp(logits), TRANSPOSED      640000
// eqh  : [NC_][100]    per-row eq[4] @0, qh[96] @8  2000000
// sg   : [64][180]     sums: d<176 = sum e^l*x, 176 = sum e^l (zeroed by kA blk0)
// tkh/tek/tvs/tvv: attn tables
#define OFF_LG   0
#define OFF_EQH  640000
#define OFF_SG   2640000
#define OFF_TKH  2651520
#define OFF_TEK  2657664
#define OFF_TVS  2657920
#define OFF_TVV  2666112

#define SGSTRIDE_ 180

// ================= kernel A: per-row logits + q-path =================
// 256 threads, 16 rows/block; grid = 625 per half; ~30.5KB LDS -> 5 blk/CU
__global__ __launch_bounds__(256) void kA(
    fptr s, fptr v,
    fptr wp_wh, fptr wp_ws_w, fptr wp_ws_b,
    fptr q_wh, fptr q_ws_w, fptr q_ws_b, fptr q_wv, fptr q_wsv_w, fptr q_wsv_b,
    fptr attn_wh, fptr attn_ws_w,
    float* __restrict__ pexp, float* __restrict__ eqh,
    float* __restrict__ sgz, const int row_base)
{
  // ARENA: phase 0-2 = XT transposed [j][row], stride 20 (16B-aligned:
  //        j*80B = 5x16B; rgA*8 floats = 32B)
  //        j: 0..127 = s, 128..143 = vn_q, 144..159 = vn_p
  //        phase 2c+ = SIG [16][128] (2048 <= 3200), aliases dead XT
  __shared__ __align__(16) float ARENA[160*XSTR_];
  __shared__ __align__(16) float VVs[ROWS_*48];
  __shared__ __align__(16) float VHQ[ROWS_*48];
  __shared__ __align__(16) float SO[ROWS_*128];
  __shared__ __align__(16) float GATE[ROWS_*16];
  __shared__ __align__(16) float QV[ROWS_*48];
  float* const XT  = ARENA;
  float* const SIG = ARENA;

  const int tid  = threadIdx.x;
  const int row0 = row_base + blockIdx.x * ROWS_;

  // first dispatch's block 0 zeroes sg (kAccum is stream-ordered after kA)
  if (blockIdx.x == 0 && row_base == 0){
    for (int i = tid; i < 64*SGSTRIDE_; i += 256) sgz[i] = 0.f;
  }

  // phase 0: stage s, v
  for (int idx = tid; idx < ROWS_*128; idx += 256){
    int r = idx >> 7, j = idx & 127;
    XT[j*XSTR_ + r] = s[(row0+r)*128 + j];
  }
  for (int idx = tid; idx < ROWS_*48; idx += 256){
    int r = idx / 48, k = idx - r*48;
    VVs[r*48 + k] = v[(row0+r)*48 + k];
  }
  __syncthreads();

  // phase 1: vh / vn, 16 rows x 32 (path,i) = 512 work items
  for (int idx = tid; idx < ROWS_*32; idx += 256){
    int r = idx >> 5, ii = idx & 31, path = ii >> 4, i = ii & 15;
    fptr wh = path ? wp_wh : q_wh;
    float h0=0.f, h1=0.f, h2=0.f;
    #pragma unroll
    for (int j = 0; j < 16; j++){
      float w = wh[j*16 + i];
      h0 = fmaf(VVs[r*48 + j*3 + 0], w, h0);
      h1 = fmaf(VVs[r*48 + j*3 + 1], w, h1);
      h2 = fmaf(VVs[r*48 + j*3 + 2], w, h2);
    }
    float vn = sqrtf(fmaxf(h0*h0 + h1*h1 + h2*h2, 1e-8f));
    if (!path){
      VHQ[r*48 +  0 + i] = h0;
      VHQ[r*48 + 16 + i] = h1;
      VHQ[r*48 + 32 + i] = h2;
      XT[(128+i)*XSTR_ + r] = vn;
    } else {
      XT[(144+i)*XSTR_ + r] = vn;
    }
  }
  __syncthreads();

  // phase 2a: so = [s, vn_q] @ q_ws_w + b  (128 cols x 2 rowgroups of 8 rows)
  const int colA = tid & 127, rgA = tid >> 7;   // rgA in {0,1}, 8 rows each
  float acc[8];
  {
    float bqs = q_ws_b[colA];
    #pragma unroll
    for (int k = 0; k < 8; k++) acc[k] = bqs;
    const float* xbA = &XT[rgA*8];
    #pragma unroll 8
    for (int j = 0; j < 144; j++){
      float w = q_ws_w[j*128 + colA];             // coalesced 64-consec/wave
      const float* xb = xbA + j*XSTR_;
      float4 x0 = *(const float4*)(xb + 0);       // wave-uniform broadcast
      float4 x1 = *(const float4*)(xb + 4);
      acc[0] = fmaf(x0.x, w, acc[0]); acc[1] = fmaf(x0.y, w, acc[1]);
      acc[2] = fmaf(x0.z, w, acc[2]); acc[3] = fmaf(x0.w, w, acc[3]);
      acc[4] = fmaf(x1.x, w, acc[4]); acc[5] = fmaf(x1.y, w, acc[5]);
      acc[6] = fmaf(x1.z, w, acc[6]); acc[7] = fmaf(x1.w, w, acc[7]);
    }
  }
  // phase 2b: logits -> store EXP(logit), TRANSPOSED pexp[(c*32+a)][n]
  // 32 cols x 8 rowgroups of 2 rows
  {
    const int colB = tid & 31, rgB = tid >> 5;    // rgB in [0,8), 2 rows each
    float b0 = wp_ws_b[colB];
    float a0 = b0, a1 = b0;
    #pragma unroll 8
    for (int j = 0; j < 144; j++){
      int jj = (j < 128) ? j : (j + 16);
      float w = wp_ws_w[j*32 + colB];
      const float* xb = &XT[jj*XSTR_ + rgB*2];
      a0 = fmaf(xb[0], w, a0);
      a1 = fmaf(xb[1], w, a1);
    }
    // rows row0 + rgB*2 + {0,1}; row0 multiple of 16 -> c = k, n = row0/2+rgB
    const int n = (row0 >> 1) + rgB;
    pexp[(0*32 + colB)*N_ + n] = __expf(a0);      // c=0  (no max-sub: |l|<~8)
    pexp[(1*32 + colB)*N_ + n] = __expf(a1);      // c=1
  }
  __syncthreads();                                // XT dead; SIG live

  // phase 2c: sig/silu once from registers
  #pragma unroll
  for (int k = 0; k < 8; k++){
    float so = acc[k];
    float sg_ = sigm(so);
    SIG[(rgA*8 + k)*128 + colA] = sg_;
    SO [(rgA*8 + k)*128 + colA] = so * sg_;       // silu
  }
  __syncthreads();

  // phase 3: gate = sigmoid(sig_so @ q_wsv_w + b)  (16 rows x 16 = 256 thr)
  {
    const int r = tid >> 4, g = tid & 15;
    float ga = q_wsv_b[g];
    #pragma unroll 8
    for (int o = 0; o < 128; o += 4){
      float4 s4 = *(const float4*)&SIG[r*128 + o];
      ga = fmaf(s4.x, q_wsv_w[(o+0)*16 + g], ga);
      ga = fmaf(s4.y, q_wsv_w[(o+1)*16 + g], ga);
      ga = fmaf(s4.z, q_wsv_w[(o+2)*16 + g], ga);
      ga = fmaf(s4.w, q_wsv_w[(o+3)*16 + g], ga);
    }
    GATE[r*16 + g] = sigm(ga);
  }
  __syncthreads();

  // phase 4 (64 items) + phase 5 (768 items) combined strided loop
  for (int t = tid; t < 64 + ROWS_*48; t += 256){
    if (t < 64){
      // eq[h] = silu_so_head . ws_q   (16 rows x 4 h)
      const int r = t >> 2, h = t & 3;
      float e = 0.f;
      #pragma unroll
      for (int u = 0; u < 32; u++)
        e = fmaf(SO[r*128 + h*32 + u], attn_ws_w[u], e);
      eqh[(row0 + r)*100 + h] = e;
    } else {
      // qv = (vh_q @ q_wv)^T * gate   (16*48 = 768 work items)
      const int t2 = t - 64;
      int r = t2 / 48, k = t2 - r*48, i = k / 3, d = k - i*3;
      float a = 0.f;
      #pragma unroll
      for (int j = 0; j < 16; j++)
        a = fmaf(VHQ[r*48 + d*16 + j], q_wv[j*16 + i], a);
      QV[r*48 + k] = a * GATE[r*16 + i];
    }
  }
  __syncthreads();

  // phase 6: qh[h][d][e] = sum_i qv[h*4+i][d] * wh_q[i][e]  (16*96 = 1536)
  for (int t = tid; t < ROWS_*96; t += 256){
    int r = t / 96, k = t - r*96;
    int h = k / 24, rem = k - h*24, d = rem >> 3, ee = rem & 7;
    float a = 0.f;
    #pragma unroll
    for (int i = 0; i < 4; i++)
      a = fmaf(QV[r*48 + (h*4 + i)*3 + d], attn_wh[i*8 + ee], a);
    eqh[(row0 + r)*100 + 8 + k] = a;
  }
}

// ===== kAccum: weighted sums via atomics, 800 blocks = 3200 waves ==========
__global__ __launch_bounds__(256) void kAccum(const float* __restrict__ pexp,
                                              fptr s, fptr v,
                                              float* __restrict__ sg)
{
  const int b = blockIdx.x;
  const int c = b & 1, ah = (b >> 1) & 1, chunk = b >> 2;
  const int n0 = chunk * 50;
  const int tid = threadIdx.x;
  const int ag = tid >> 6, dl = tid & 63;
  const int abase = ah*16 + ag*4;

  const float* pb = pexp + (c*32 + abase)*N_;
  float acc[4][3] = {};
  float dn[4] = {};

  #pragma unroll 2
  for (int n = n0; n < n0 + 50; n++){
    const int rc = n*2 + c;
    float pw[4];
    #pragma unroll
    for (int aa = 0; aa < 4; aa++){
      pw[aa] = pb[aa*N_ + n];
      dn[aa] += pw[aa];
    }
    #pragma unroll
    for (int dd = 0; dd < 3; dd++){
      int d = dl + 64*dd;
      if (d < 176){
        float xv = (d < 128) ? s[rc*128 + d] : v[rc*48 + d - 128];
        #pragma unroll
        for (int aa = 0; aa < 4; aa++)
          acc[aa][dd] = fmaf(pw[aa], xv, acc[aa][dd]);
      }
    }
  }
  #pragma unroll
  for (int aa = 0; aa < 4; aa++){
    const int base = (c*32 + abase + aa)*SGSTRIDE_;
    #pragma unroll
    for (int dd = 0; dd < 3; dd++){
      int d = dl + 64*dd;
      if (d < 176) atomicAdd(&sg[base + d], acc[aa][dd]);
    }
    if (dl == 0) atomicAdd(&sg[base + 176], dn[aa]);
  }
}

// ================= kSmall: normalize + k/vv GVP + attn tables ===============
__global__ __launch_bounds__(256) void kSmall(
    const float* __restrict__ sg,
    fptr k_wh, fptr k_ws_w, fptr k_ws_b, fptr k_wv, fptr k_wsv_w, fptr k_wsv_b,
    fptr vv_wh, fptr vv_ws_w, fptr vv_ws_b, fptr vv_wv, fptr vv_wsv_w, fptr vv_wsv_b,
    fptr attn_wh, fptr attn_ws_w,
    float* __restrict__ tkh, float* __restrict__ tek,
    float* __restrict__ tvs, float* __restrict__ tvv)
{
  const int b = blockIdx.x, r = b >> 1, c = b & 1;
  const int tid = threadIdx.x;
  __shared__ float X[176];
  __shared__ float VN[2][16];
  __shared__ float VH[2][48];
  __shared__ float SOk[128], SOv[128];
  __shared__ float G[2][16];
  __shared__ float KV[48];

  if (tid < 176){
    const float* p = sg + (c*32 + r)*SGSTRIDE_;
    X[tid] = p[tid] / p[176];
  }
  __syncthreads();

  if (tid < 32){
    int path = tid >> 4, i = tid & 15;
    fptr wh = path ? vv_wh : k_wh;
    float h0=0.f, h1=0.f, h2=0.f;
    #pragma unroll
    for (int j = 0; j < 16; j++){
      float w = wh[j*16 + i];
      h0 = fmaf(X[128 + j*3 + 0], w, h0);
      h1 = fmaf(X[128 + j*3 + 1], w, h1);
      h2 = fmaf(X[128 + j*3 + 2], w, h2);
    }
    VH[path][ 0 + i] = h0; VH[path][16 + i] = h1; VH[path][32 + i] = h2;
    VN[path][i] = sqrtf(fmaxf(h0*h0 + h1*h1 + h2*h2, 1e-8f));
  }
  __syncthreads();

  {
    int path = tid >> 7, col = tid & 127;
    fptr W  = path ? vv_ws_w : k_ws_w;
    fptr Bb = path ? vv_ws_b : k_ws_b;
    float so = Bb[col];
    for (int j = 0; j < 128; j++) so = fmaf(X[j], W[j*128 + col], so);
    #pragma unroll
    for (int i = 0; i < 16; i++)  so = fmaf(VN[path][i], W[(128+i)*128 + col], so);
    (path ? SOv : SOk)[col] = so;
  }
  __syncthreads();

  if (tid < 32){
    int path = tid >> 4, g = tid & 15;
    fptr Wsv = path ? vv_wsv_w : k_wsv_w;
    fptr Bsv = path ? vv_wsv_b : k_wsv_b;
    const float* SOp = path ? SOv : SOk;
    float ga = Bsv[g];
    for (int o = 0; o < 128; o++)
      ga = fmaf(sigm(SOp[o]), Wsv[o*16 + g], ga);
    G[path][g] = sigm(ga);
  } else if (tid < 36){
    int h = tid - 32;
    float e = 0.f;
    #pragma unroll
    for (int t = 0; t < 32; t++){
      float so = SOk[h*32 + t];
      e = fmaf(so * sigm(so), attn_ws_w[32 + t], e);
    }
    tek[(r*2 + c)*4 + h] = e;
  } else if (tid >= 64 && tid < 192){
    int o = tid - 64;
    float so = SOv[o];
    tvs[(r*2 + c)*128 + o] = so * sigm(so);
  }
  __syncthreads();

  if (tid < 96){
    int path = tid / 48, k = tid % 48, i = k / 3, d = k - i*3;
    fptr Wv = path ? vv_wv : k_wv;
    float vo = 0.f;
    #pragma unroll
    for (int j = 0; j < 16; j++)
      vo = fmaf(VH[path][d*16 + j], Wv[j*16 + i], vo);
    float gv = vo * G[path][i];
    if (path == 0) KV[k] = gv;
    else {
      int h = i >> 2, ii = i & 3;
      tvv[(((r*2 + c)*4 + h)*4 + ii)*3 + d] = gv;
    }
  }
  __syncthreads();

  if (tid < 96){
    int h = tid / 24, rem = tid % 24, d = rem >> 3, ee = rem & 7;
    float a = 0.f;
    #pragma unroll
    for (int i = 0; i < 4; i++)
      a = fmaf(KV[(h*4 + i)*3 + d], attn_wh[(4 + i)*8 + ee], a);
    tkh[((r*2 + c)*4 + h)*24 + d*8 + ee] = a;
  }
}

// ================= kAttn (R9-measured): one row/thread ======================
__global__ __launch_bounds__(512, 1) void kAttn(
    const float* __restrict__ eqh,
    const float* __restrict__ tkh, const float* __restrict__ tek,
    const float* __restrict__ tvs, const float* __restrict__ tvv,
    fptr attn_ws_w, fptr attn_ws_b,
    float* __restrict__ out)
{
  __shared__ __align__(16) float KH[6144];
  __shared__ __align__(16) float EK[256];
  __shared__ __align__(16) float VS[256*36];
  __shared__ __align__(16) float VVt[3072];
  const int tid = threadIdx.x;

  for (int i = tid; i < 6144; i += 512) KH[i] = tkh[i];
  if (tid < 256) EK[tid] = tek[tid];
  for (int i = tid; i < 8192; i += 512){ int base = i >> 5, t = i & 31; VS[base*36 + t] = tvs[i]; }
  for (int i = tid; i < 3072; i += 512) VVt[i] = tvv[i];

  float wsn[8];
  #pragma unroll
  for (int ee = 0; ee < 8; ee++) wsn[ee] = attn_ws_w[64 + ee];
  const float wb = attn_ws_b[0];
  __syncthreads();

  const int row = blockIdx.x*128 + (tid >> 2);
  const int h = tid & 3;
  if (row < NC_){
    const int c = row & 1;
    const float eq = eqh[row*100 + h];
    float qh[24];
    {
      const float4* qp = (const float4*)&eqh[row*100 + 8 + h*24];
      #pragma unroll
      for (int k = 0; k < 6; k++){
        float4 t4 = qp[k];
        qh[k*4+0] = t4.x; qh[k*4+1] = t4.y; qh[k*4+2] = t4.z; qh[k*4+3] = t4.w;
      }
    }
    float4 accs4[8];
    float4 accv4[3];
    #pragma unroll
    for (int q = 0; q < 8; q++) accs4[q] = make_float4(0.f,0.f,0.f,0.f);
    #pragma unroll
    for (int q = 0; q < 3; q++) accv4[q] = make_float4(0.f,0.f,0.f,0.f);
    float den = 0.f;

    #pragma unroll
    for (int r = 0; r < 32; r++){
      const int base = (r*2 + c)*4 + h;
      const float* khp = &KH[base*24];
      float en = 0.f;
      #pragma unroll
      for (int ee = 0; ee < 8; ee++){
        float a0 = qh[ee]      + khp[ee];
        float a1 = qh[8 + ee]  + khp[8 + ee];
        float a2 = qh[16 + ee] + khp[16 + ee];
        en = fmaf(sqrtf(fmaxf(a0*a0 + a1*a1 + a2*a2, 1e-8f)), wsn[ee], en);
      }
      const float w = __expf((eq + EK[base] + en + wb) * 0.17677669529663687f);
      den += w;
      const float4* vp4 = (const float4*)&VS[base*36];
      #pragma unroll
      for (int q = 0; q < 8; q++){
        float4 t4 = vp4[q];
        accs4[q].x = fmaf(w, t4.x, accs4[q].x);
        accs4[q].y = fmaf(w, t4.y, accs4[q].y);
        accs4[q].z = fmaf(w, t4.z, accs4[q].z);
        accs4[q].w = fmaf(w, t4.w, accs4[q].w);
      }
      const float4* vv4 = (const float4*)&VVt[base*12];
      #pragma unroll
      for (int q = 0; q < 3; q++){
        float4 t4 = vv4[q];
        accv4[q].x = fmaf(w, t4.x, accv4[q].x);
        accv4[q].y = fmaf(w, t4.y, accv4[q].y);
        accv4[q].z = fmaf(w, t4.z, accv4[q].z);
        accv4[q].w = fmaf(w, t4.w, accv4[q].w);
      }
    }
    const float inv = 1.f / den;
    float4* po = (float4*)&out[row*128 + h*32];
    #pragma unroll
    for (int q = 0; q < 8; q++){
      float4 t4 = accs4[q];
      t4.x *= inv; t4.y *= inv; t4.z *= inv; t4.w *= inv;
      po[q] = t4;
    }
    float4* pv = (float4*)&out[NC_*128 + row*48 + h*12];
    #pragma unroll
    for (int q = 0; q < 3; q++){
      float4 t4 = accv4[q];
      t4.x *= inv; t4.y *= inv; t4.z *= inv; t4.w *= inv;
      pv[q] = t4;
    }
  }
}

extern "C" void kernel_launch(void* const* d_in, const int* in_sizes, int n_in,
                              void* d_out, int out_size, void* d_ws, size_t ws_size,
                              hipStream_t stream)
{
  fptr s        = (fptr)d_in[0];
  fptr v        = (fptr)d_in[1];
  fptr wp_wh    = (fptr)d_in[2];
  fptr wp_ws_w  = (fptr)d_in[3];
  fptr wp_ws_b  = (fptr)d_in[4];
  fptr q_wh     = (fptr)d_in[5];
  fptr q_ws_w   = (fptr)d_in[6];
  fptr q_ws_b   = (fptr)d_in[7];
  fptr q_wv     = (fptr)d_in[8];
  fptr q_wsv_w  = (fptr)d_in[9];
  fptr q_wsv_b  = (fptr)d_in[10];
  fptr k_wh     = (fptr)d_in[11];
  fptr k_ws_w   = (fptr)d_in[12];
  fptr k_ws_b   = (fptr)d_in[13];
  fptr k_wv     = (fptr)d_in[14];
  fptr k_wsv_w  = (fptr)d_in[15];
  fptr k_wsv_b  = (fptr)d_in[16];
  fptr vv_wh    = (fptr)d_in[17];
  fptr vv_ws_w  = (fptr)d_in[18];
  fptr vv_ws_b  = (fptr)d_in[19];
  fptr vv_wv    = (fptr)d_in[20];
  fptr vv_wsv_w = (fptr)d_in[21];
  fptr vv_wsv_b = (fptr)d_in[22];
  fptr attn_wh  = (fptr)d_in[23];
  fptr attn_ws_w= (fptr)d_in[24];
  fptr attn_ws_b= (fptr)d_in[25];

  float* ws   = (float*)d_ws;
  float* pexp = ws + OFF_LG;
  float* eqh  = ws + OFF_EQH;
  float* sg   = ws + OFF_SG;
  float* tkh  = ws + OFF_TKH;
  float* tek  = ws + OFF_TEK;
  float* tvs  = ws + OFF_TVS;
  float* tvv  = ws + OFF_TVV;

  // kA split into two half-grid dispatches (diagnostic: lowers the top-5
  // cutoff below kAccum/kSmall/kAttn so their counters become visible)
  kA<<<625, 256, 0, stream>>>(s, v, wp_wh, wp_ws_w, wp_ws_b,
                              q_wh, q_ws_w, q_ws_b, q_wv, q_wsv_w, q_wsv_b,
                              attn_wh, attn_ws_w, pexp, eqh, sg, 0);
  kA<<<625, 256, 0, stream>>>(s, v, wp_wh, wp_ws_w, wp_ws_b,
                              q_wh, q_ws_w, q_ws_b, q_wv, q_wsv_w, q_wsv_b,
                              attn_wh, attn_ws_w, pexp, eqh, sg, 10000);
  kAccum<<<800, 256, 0, stream>>>(pexp, s, v, sg);
  kSmall<<<64, 256, 0, stream>>>(sg,
                                 k_wh, k_ws_w, k_ws_b, k_wv, k_wsv_w, k_wsv_b,
                                 vv_wh, vv_ws_w, vv_ws_b, vv_wv, vv_wsv_w, vv_wsv_b,
                                 attn_wh, attn_ws_w, tkh, tek, tvs, tvv);
  kAttn<<<(NC_ + 127)/128, 512, 0, stream>>>(eqh, tkh, tek, tvs, tvv,
                                             attn_ws_w, attn_ws_b, (float*)d_out);
}

// Round 6
// 233.905 us; speedup vs baseline: 1.1887x; 1.0700x over previous
//
#include <hip/hip_runtime.h>
#include <hip/hip_bf16.h>

// GVPDynamicProjection: N=10000, C=2, SI=128, VI=16, H=4, R=32, SH=32, VH=4
// R19 = R16 kA (single dispatch, best-known 47us) + restructured kAttn.
// R18 diagnostic found the hidden ~192us: fillBuffer 43us (harness ws
// re-poison, HBM-roofline, untouchable), kAttn 43us (grid 157 blocks -> 99
// CUs idle, 73KB LDS -> 1 block/CU, occupancy 10%), rest ~70us still hidden.
// kAttn fix: block = (64-row tile x one h) -> per-h tables, LDS 73->19.7KB;
// r-loop split 4-way across threads (thread=(row,rh), 8 r each, partials
// combined via 2 __shfl_xor stages); grid 157 -> 1252 blocks (~4.9/CU,
// ~20 waves/CU). KH stride padded 24->28 (VS 36, VV 12) keeps every DS
// access <=2 addresses/bank for the new lane mixture (free tier, m136).
// kAccum / kSmall byte-identical to R13/R16.

#define N_  10000
#define C_  2
#define SI_ 128
#define VI_ 16
#define H_  4
#define R_  32
#define SH_ 32
#define VH_ 4
#define NC_ (N_*C_)

#define ROWS_ 16
#define XSTR_ 20   // XT leading stride: 16 rows + 4 pad; 80B = 5x16B aligned

typedef const float* __restrict__ fptr;

__device__ __forceinline__ float sigm(float x){ return 1.f/(1.f+__expf(-x)); }

// ---------------- ws layout (float offsets) ----------------
// pexp : [C_*32][N_]   exp(logits), TRANSPOSED      640000
// eqh  : [NC_][100]    per-row eq[4] @0, qh[96] @8  2000000
// sg   : [64][180]     sums: d<176 = sum e^l*x, 176 = sum e^l (zeroed by kA blk0)
// tkh/tek/tvs/tvv: attn tables
#define OFF_LG   0
#define OFF_EQH  640000
#define OFF_SG   2640000
#define OFF_TKH  2651520
#define OFF_TEK  2657664
#define OFF_TVS  2657920
#define OFF_TVV  2666112

#define SGSTRIDE_ 180

// ================= kernel A: per-row logits + q-path =================
// 256 threads, 16 rows/block; grid = NC_/16 = 1250; ~30.5KB LDS -> 5 blk/CU
__global__ __launch_bounds__(256) void kA(
    fptr s, fptr v,
    fptr wp_wh, fptr wp_ws_w, fptr wp_ws_b,
    fptr q_wh, fptr q_ws_w, fptr q_ws_b, fptr q_wv, fptr q_wsv_w, fptr q_wsv_b,
    fptr attn_wh, fptr attn_ws_w,
    float* __restrict__ pexp, float* __restrict__ eqh,
    float* __restrict__ sgz)
{
  // ARENA: phase 0-2 = XT transposed [j][row], stride 20 (16B-aligned:
  //        j*80B = 5x16B; rgA*8 floats = 32B)
  //        j: 0..127 = s, 128..143 = vn_q, 144..159 = vn_p
  //        phase 2c+ = SIG [16][128] (2048 <= 3200), aliases dead XT
  __shared__ __align__(16) float ARENA[160*XSTR_];
  __shared__ __align__(16) float VVs[ROWS_*48];
  __shared__ __align__(16) float VHQ[ROWS_*48];
  __shared__ __align__(16) float SO[ROWS_*128];
  __shared__ __align__(16) float GATE[ROWS_*16];
  __shared__ __align__(16) float QV[ROWS_*48];
  float* const XT  = ARENA;
  float* const SIG = ARENA;

  const int tid  = threadIdx.x;
  const int row0 = blockIdx.x * ROWS_;

  // block 0 also zeroes sg (kAccum is stream-ordered after all kA blocks)
  if (blockIdx.x == 0){
    for (int i = tid; i < 64*SGSTRIDE_; i += 256) sgz[i] = 0.f;
  }

  // phase 0: stage s, v
  for (int idx = tid; idx < ROWS_*128; idx += 256){
    int r = idx >> 7, j = idx & 127;
    XT[j*XSTR_ + r] = s[(row0+r)*128 + j];
  }
  for (int idx = tid; idx < ROWS_*48; idx += 256){
    int r = idx / 48, k = idx - r*48;
    VVs[r*48 + k] = v[(row0+r)*48 + k];
  }
  __syncthreads();

  // phase 1: vh / vn, 16 rows x 32 (path,i) = 512 work items
  for (int idx = tid; idx < ROWS_*32; idx += 256){
    int r = idx >> 5, ii = idx & 31, path = ii >> 4, i = ii & 15;
    fptr wh = path ? wp_wh : q_wh;
    float h0=0.f, h1=0.f, h2=0.f;
    #pragma unroll
    for (int j = 0; j < 16; j++){
      float w = wh[j*16 + i];
      h0 = fmaf(VVs[r*48 + j*3 + 0], w, h0);
      h1 = fmaf(VVs[r*48 + j*3 + 1], w, h1);
      h2 = fmaf(VVs[r*48 + j*3 + 2], w, h2);
    }
    float vn = sqrtf(fmaxf(h0*h0 + h1*h1 + h2*h2, 1e-8f));
    if (!path){
      VHQ[r*48 +  0 + i] = h0;
      VHQ[r*48 + 16 + i] = h1;
      VHQ[r*48 + 32 + i] = h2;
      XT[(128+i)*XSTR_ + r] = vn;
    } else {
      XT[(144+i)*XSTR_ + r] = vn;
    }
  }
  __syncthreads();

  // phase 2a: so = [s, vn_q] @ q_ws_w + b  (128 cols x 2 rowgroups of 8 rows)
  const int colA = tid & 127, rgA = tid >> 7;   // rgA in {0,1}, 8 rows each
  float acc[8];
  {
    float bqs = q_ws_b[colA];
    #pragma unroll
    for (int k = 0; k < 8; k++) acc[k] = bqs;
    const float* xbA = &XT[rgA*8];
    #pragma unroll 8
    for (int j = 0; j < 144; j++){
      float w = q_ws_w[j*128 + colA];             // coalesced 64-consec/wave
      const float* xb = xbA + j*XSTR_;
      float4 x0 = *(const float4*)(xb + 0);       // wave-uniform broadcast
      float4 x1 = *(const float4*)(xb + 4);
      acc[0] = fmaf(x0.x, w, acc[0]); acc[1] = fmaf(x0.y, w, acc[1]);
      acc[2] = fmaf(x0.z, w, acc[2]); acc[3] = fmaf(x0.w, w, acc[3]);
      acc[4] = fmaf(x1.x, w, acc[4]); acc[5] = fmaf(x1.y, w, acc[5]);
      acc[6] = fmaf(x1.z, w, acc[6]); acc[7] = fmaf(x1.w, w, acc[7]);
    }
  }
  // phase 2b: logits -> store EXP(logit), TRANSPOSED pexp[(c*32+a)][n]
  // 32 cols x 8 rowgroups of 2 rows
  {
    const int colB = tid & 31, rgB = tid >> 5;    // rgB in [0,8), 2 rows each
    float b0 = wp_ws_b[colB];
    float a0 = b0, a1 = b0;
    #pragma unroll 8
    for (int j = 0; j < 144; j++){
      int jj = (j < 128) ? j : (j + 16);
      float w = wp_ws_w[j*32 + colB];
      const float* xb = &XT[jj*XSTR_ + rgB*2];
      a0 = fmaf(xb[0], w, a0);
      a1 = fmaf(xb[1], w, a1);
    }
    // rows row0 + rgB*2 + {0,1}; row0 multiple of 16 -> c = k, n = row0/2+rgB
    const int n = (row0 >> 1) + rgB;
    pexp[(0*32 + colB)*N_ + n] = __expf(a0);      // c=0  (no max-sub: |l|<~8)
    pexp[(1*32 + colB)*N_ + n] = __expf(a1);      // c=1
  }
  __syncthreads();                                // XT dead; SIG live

  // phase 2c: sig/silu once from registers
  #pragma unroll
  for (int k = 0; k < 8; k++){
    float so = acc[k];
    float sg_ = sigm(so);
    SIG[(rgA*8 + k)*128 + colA] = sg_;
    SO [(rgA*8 + k)*128 + colA] = so * sg_;       // silu
  }
  __syncthreads();

  // phase 3: gate = sigmoid(sig_so @ q_wsv_w + b)  (16 rows x 16 = 256 thr)
  {
    const int r = tid >> 4, g = tid & 15;
    float ga = q_wsv_b[g];
    #pragma unroll 8
    for (int o = 0; o < 128; o += 4){
      float4 s4 = *(const float4*)&SIG[r*128 + o];
      ga = fmaf(s4.x, q_wsv_w[(o+0)*16 + g], ga);
      ga = fmaf(s4.y, q_wsv_w[(o+1)*16 + g], ga);
      ga = fmaf(s4.z, q_wsv_w[(o+2)*16 + g], ga);
      ga = fmaf(s4.w, q_wsv_w[(o+3)*16 + g], ga);
    }
    GATE[r*16 + g] = sigm(ga);
  }
  __syncthreads();

  // phase 4 (64 items) + phase 5 (768 items) combined strided loop
  for (int t = tid; t < 64 + ROWS_*48; t += 256){
    if (t < 64){
      // eq[h] = silu_so_head . ws_q   (16 rows x 4 h)
      const int r = t >> 2, h = t & 3;
      float e = 0.f;
      #pragma unroll
      for (int u = 0; u < 32; u++)
        e = fmaf(SO[r*128 + h*32 + u], attn_ws_w[u], e);
      eqh[(row0 + r)*100 + h] = e;
    } else {
      // qv = (vh_q @ q_wv)^T * gate   (16*48 = 768 work items)
      const int t2 = t - 64;
      int r = t2 / 48, k = t2 - r*48, i = k / 3, d = k - i*3;
      float a = 0.f;
      #pragma unroll
      for (int j = 0; j < 16; j++)
        a = fmaf(VHQ[r*48 + d*16 + j], q_wv[j*16 + i], a);
      QV[r*48 + k] = a * GATE[r*16 + i];
    }
  }
  __syncthreads();

  // phase 6: qh[h][d][e] = sum_i qv[h*4+i][d] * wh_q[i][e]  (16*96 = 1536)
  for (int t = tid; t < ROWS_*96; t += 256){
    int r = t / 96, k = t - r*96;
    int h = k / 24, rem = k - h*24, d = rem >> 3, ee = rem & 7;
    float a = 0.f;
    #pragma unroll
    for (int i = 0; i < 4; i++)
      a = fmaf(QV[r*48 + (h*4 + i)*3 + d], attn_wh[i*8 + ee], a);
    eqh[(row0 + r)*100 + 8 + k] = a;
  }
}

// ===== kAccum: weighted sums via atomics, 800 blocks = 3200 waves ==========
__global__ __launch_bounds__(256) void kAccum(const float* __restrict__ pexp,
                                              fptr s, fptr v,
                                              float* __restrict__ sg)
{
  const int b = blockIdx.x;
  const int c = b & 1, ah = (b >> 1) & 1, chunk = b >> 2;
  const int n0 = chunk * 50;
  const int tid = threadIdx.x;
  const int ag = tid >> 6, dl = tid & 63;
  const int abase = ah*16 + ag*4;

  const float* pb = pexp + (c*32 + abase)*N_;
  float acc[4][3] = {};
  float dn[4] = {};

  #pragma unroll 2
  for (int n = n0; n < n0 + 50; n++){
    const int rc = n*2 + c;
    float pw[4];
    #pragma unroll
    for (int aa = 0; aa < 4; aa++){
      pw[aa] = pb[aa*N_ + n];
      dn[aa] += pw[aa];
    }
    #pragma unroll
    for (int dd = 0; dd < 3; dd++){
      int d = dl + 64*dd;
      if (d < 176){
        float xv = (d < 128) ? s[rc*128 + d] : v[rc*48 + d - 128];
        #pragma unroll
        for (int aa = 0; aa < 4; aa++)
          acc[aa][dd] = fmaf(pw[aa], xv, acc[aa][dd]);
      }
    }
  }
  #pragma unroll
  for (int aa = 0; aa < 4; aa++){
    const int base = (c*32 + abase + aa)*SGSTRIDE_;
    #pragma unroll
    for (int dd = 0; dd < 3; dd++){
      int d = dl + 64*dd;
      if (d < 176) atomicAdd(&sg[base + d], acc[aa][dd]);
    }
    if (dl == 0) atomicAdd(&sg[base + 176], dn[aa]);
  }
}

// ================= kSmall: normalize + k/vv GVP + attn tables ===============
__global__ __launch_bounds__(256) void kSmall(
    const float* __restrict__ sg,
    fptr k_wh, fptr k_ws_w, fptr k_ws_b, fptr k_wv, fptr k_wsv_w, fptr k_wsv_b,
    fptr vv_wh, fptr vv_ws_w, fptr vv_ws_b, fptr vv_wv, fptr vv_wsv_w, fptr vv_wsv_b,
    fptr attn_wh, fptr attn_ws_w,
    float* __restrict__ tkh, float* __restrict__ tek,
    float* __restrict__ tvs, float* __restrict__ tvv)
{
  const int b = blockIdx.x, r = b >> 1, c = b & 1;
  const int tid = threadIdx.x;
  __shared__ float X[176];
  __shared__ float VN[2][16];
  __shared__ float VH[2][48];
  __shared__ float SOk[128], SOv[128];
  __shared__ float G[2][16];
  __shared__ float KV[48];

  if (tid < 176){
    const float* p = sg + (c*32 + r)*SGSTRIDE_;
    X[tid] = p[tid] / p[176];
  }
  __syncthreads();

  if (tid < 32){
    int path = tid >> 4, i = tid & 15;
    fptr wh = path ? vv_wh : k_wh;
    float h0=0.f, h1=0.f, h2=0.f;
    #pragma unroll
    for (int j = 0; j < 16; j++){
      float w = wh[j*16 + i];
      h0 = fmaf(X[128 + j*3 + 0], w, h0);
      h1 = fmaf(X[128 + j*3 + 1], w, h1);
      h2 = fmaf(X[128 + j*3 + 2], w, h2);
    }
    VH[path][ 0 + i] = h0; VH[path][16 + i] = h1; VH[path][32 + i] = h2;
    VN[path][i] = sqrtf(fmaxf(h0*h0 + h1*h1 + h2*h2, 1e-8f));
  }
  __syncthreads();

  {
    int path = tid >> 7, col = tid & 127;
    fptr W  = path ? vv_ws_w : k_ws_w;
    fptr Bb = path ? vv_ws_b : k_ws_b;
    float so = Bb[col];
    for (int j = 0; j < 128; j++) so = fmaf(X[j], W[j*128 + col], so);
    #pragma unroll
    for (int i = 0; i < 16; i++)  so = fmaf(VN[path][i], W[(128+i)*128 + col], so);
    (path ? SOv : SOk)[col] = so;
  }
  __syncthreads();

  if (tid < 32){
    int path = tid >> 4, g = tid & 15;
    fptr Wsv = path ? vv_wsv_w : k_wsv_w;
    fptr Bsv = path ? vv_wsv_b : k_wsv_b;
    const float* SOp = path ? SOv : SOk;
    float ga = Bsv[g];
    for (int o = 0; o < 128; o++)
      ga = fmaf(sigm(SOp[o]), Wsv[o*16 + g], ga);
    G[path][g] = sigm(ga);
  } else if (tid < 36){
    int h = tid - 32;
    float e = 0.f;
    #pragma unroll
    for (int t = 0; t < 32; t++){
      float so = SOk[h*32 + t];
      e = fmaf(so * sigm(so), attn_ws_w[32 + t], e);
    }
    tek[(r*2 + c)*4 + h] = e;
  } else if (tid >= 64 && tid < 192){
    int o = tid - 64;
    float so = SOv[o];
    tvs[(r*2 + c)*128 + o] = so * sigm(so);
  }
  __syncthreads();

  if (tid < 96){
    int path = tid / 48, k = tid % 48, i = k / 3, d = k - i*3;
    fptr Wv = path ? vv_wv : k_wv;
    float vo = 0.f;
    #pragma unroll
    for (int j = 0; j < 16; j++)
      vo = fmaf(VH[path][d*16 + j], Wv[j*16 + i], vo);
    float gv = vo * G[path][i];
    if (path == 0) KV[k] = gv;
    else {
      int h = i >> 2, ii = i & 3;
      tvv[(((r*2 + c)*4 + h)*4 + ii)*3 + d] = gv;
    }
  }
  __syncthreads();

  if (tid < 96){
    int h = tid / 24, rem = tid % 24, d = rem >> 3, ee = rem & 7;
    float a = 0.f;
    #pragma unroll
    for (int i = 0; i < 4; i++)
      a = fmaf(KV[(h*4 + i)*3 + d], attn_wh[(4 + i)*8 + ee], a);
    tkh[((r*2 + c)*4 + h)*24 + d*8 + ee] = a;
  }
}

// ================= kAttn (R19): block = 64 rows x one h ====================
// 256 threads = 64 rows x 4 r-quarters; grid = 313*4 = 1252.
// Per-h LDS tables: KH[64][28] (pad 24->28), VS[64][36], VV[64][12], EK[64]
// = 19.7KB. Thread (row,rh) accumulates r in [rh*8, rh*8+8); partials
// combined via __shfl_xor 1,2 (quad = one row, 4 rh). All DS reads land
// <=2 addresses/bank (derived for m = 2r+c lane mixture).
__global__ __launch_bounds__(256) void kAttn(
    const float* __restrict__ eqh,
    const float* __restrict__ tkh, const float* __restrict__ tek,
    const float* __restrict__ tvs, const float* __restrict__ tvv,
    fptr attn_ws_w, fptr attn_ws_b,
    float* __restrict__ out)
{
  __shared__ __align__(16) float KH[64*28];
  __shared__ __align__(16) float VS[64*36];
  __shared__ __align__(16) float VV[64*12];
  __shared__ float EK[64];
  const int tid = threadIdx.x;
  const int h      = blockIdx.x & 3;
  const int rowblk = blockIdx.x >> 2;

  // stage this h's tables (m = r*2+c in [0,64))
  for (int i = tid; i < 64*24; i += 256){
    int m = i / 24, t = i - m*24;
    KH[m*28 + t] = tkh[(m*4 + h)*24 + t];
  }
  for (int i = tid; i < 64*32; i += 256){
    int m = i >> 5, t = i & 31;
    VS[m*36 + t] = tvs[m*128 + h*32 + t];
  }
  for (int i = tid; i < 64*12; i += 256){
    int m = i / 12, t = i - m*12;
    VV[m*12 + t] = tvv[(m*4 + h)*12 + t];
  }
  if (tid < 64) EK[tid] = tek[tid*4 + h];

  float wsn[8];
  #pragma unroll
  for (int ee = 0; ee < 8; ee++) wsn[ee] = attn_ws_w[64 + ee];
  const float wb = attn_ws_b[0];
  __syncthreads();

  const int rh  = tid & 3;                  // r-quarter
  const int row = rowblk*64 + (tid >> 2);   // quad (4 lanes) = one row
  if (row < NC_){
    const int c = row & 1;
    const float eq = eqh[row*100 + h];
    float qh[24];
    {
      const float4* qp = (const float4*)&eqh[row*100 + 8 + h*24];
      #pragma unroll
      for (int k = 0; k < 6; k++){
        float4 t4 = qp[k];
        qh[k*4+0] = t4.x; qh[k*4+1] = t4.y; qh[k*4+2] = t4.z; qh[k*4+3] = t4.w;
      }
    }
    float4 accs4[8];
    float4 accv4[3];
    #pragma unroll
    for (int q = 0; q < 8; q++) accs4[q] = make_float4(0.f,0.f,0.f,0.f);
    #pragma unroll
    for (int q = 0; q < 3; q++) accv4[q] = make_float4(0.f,0.f,0.f,0.f);
    float den = 0.f;

    #pragma unroll
    for (int rr = 0; rr < 8; rr++){
      const int m = (rh*8 + rr)*2 + c;
      const float* khp = &KH[m*28];
      float en = 0.f;
      #pragma unroll
      for (int ee = 0; ee < 8; ee++){
        float a0 = qh[ee]      + khp[ee];
        float a1 = qh[8 + ee]  + khp[8 + ee];
        float a2 = qh[16 + ee] + khp[16 + ee];
        en = fmaf(sqrtf(fmaxf(a0*a0 + a1*a1 + a2*a2, 1e-8f)), wsn[ee], en);
      }
      const float w = __expf((eq + EK[m] + en + wb) * 0.17677669529663687f);
      den += w;
      const float4* vp4 = (const float4*)&VS[m*36];
      #pragma unroll
      for (int q = 0; q < 8; q++){
        float4 t4 = vp4[q];
        accs4[q].x = fmaf(w, t4.x, accs4[q].x);
        accs4[q].y = fmaf(w, t4.y, accs4[q].y);
        accs4[q].z = fmaf(w, t4.z, accs4[q].z);
        accs4[q].w = fmaf(w, t4.w, accs4[q].w);
      }
      const float4* vv4 = (const float4*)&VV[m*12];
      #pragma unroll
      for (int q = 0; q < 3; q++){
        float4 t4 = vv4[q];
        accv4[q].x = fmaf(w, t4.x, accv4[q].x);
        accv4[q].y = fmaf(w, t4.y, accv4[q].y);
        accv4[q].z = fmaf(w, t4.z, accv4[q].z);
        accv4[q].w = fmaf(w, t4.w, accv4[q].w);
      }
    }

    // combine the 4 r-quarters within each row-quad (lanes xor 1, xor 2)
    #pragma unroll
    for (int q = 0; q < 8; q++){
      accs4[q].x += __shfl_xor(accs4[q].x, 1, 64);
      accs4[q].x += __shfl_xor(accs4[q].x, 2, 64);
      accs4[q].y += __shfl_xor(accs4[q].y, 1, 64);
      accs4[q].y += __shfl_xor(accs4[q].y, 2, 64);
      accs4[q].z += __shfl_xor(accs4[q].z, 1, 64);
      accs4[q].z += __shfl_xor(accs4[q].z, 2, 64);
      accs4[q].w += __shfl_xor(accs4[q].w, 1, 64);
      accs4[q].w += __shfl_xor(accs4[q].w, 2, 64);
    }
    #pragma unroll
    for (int q = 0; q < 3; q++){
      accv4[q].x += __shfl_xor(accv4[q].x, 1, 64);
      accv4[q].x += __shfl_xor(accv4[q].x, 2, 64);
      accv4[q].y += __shfl_xor(accv4[q].y, 1, 64);
      accv4[q].y += __shfl_xor(accv4[q].y, 2, 64);
      accv4[q].z += __shfl_xor(accv4[q].z, 1, 64);
      accv4[q].z += __shfl_xor(accv4[q].z, 2, 64);
      accv4[q].w += __shfl_xor(accv4[q].w, 1, 64);
      accv4[q].w += __shfl_xor(accv4[q].w, 2, 64);
    }
    den += __shfl_xor(den, 1, 64);
    den += __shfl_xor(den, 2, 64);

    if (rh == 0){
      const float inv = 1.f / den;
      float4* po = (float4*)&out[row*128 + h*32];
      #pragma unroll
      for (int q = 0; q < 8; q++){
        float4 t4 = accs4[q];
        t4.x *= inv; t4.y *= inv; t4.z *= inv; t4.w *= inv;
        po[q] = t4;
      }
      float4* pv = (float4*)&out[NC_*128 + row*48 + h*12];
      #pragma unroll
      for (int q = 0; q < 3; q++){
        float4 t4 = accv4[q];
        t4.x *= inv; t4.y *= inv; t4.z *= inv; t4.w *= inv;
        pv[q] = t4;
      }
    }
  }
}

extern "C" void kernel_launch(void* const* d_in, const int* in_sizes, int n_in,
                              void* d_out, int out_size, void* d_ws, size_t ws_size,
                              hipStream_t stream)
{
  fptr s        = (fptr)d_in[0];
  fptr v        = (fptr)d_in[1];
  fptr wp_wh    = (fptr)d_in[2];
  fptr wp_ws_w  = (fptr)d_in[3];
  fptr wp_ws_b  = (fptr)d_in[4];
  fptr q_wh     = (fptr)d_in[5];
  fptr q_ws_w   = (fptr)d_in[6];
  fptr q_ws_b   = (fptr)d_in[7];
  fptr q_wv     = (fptr)d_in[8];
  fptr q_wsv_w  = (fptr)d_in[9];
  fptr q_wsv_b  = (fptr)d_in[10];
  fptr k_wh     = (fptr)d_in[11];
  fptr k_ws_w   = (fptr)d_in[12];
  fptr k_ws_b   = (fptr)d_in[13];
  fptr k_wv     = (fptr)d_in[14];
  fptr k_wsv_w  = (fptr)d_in[15];
  fptr k_wsv_b  = (fptr)d_in[16];
  fptr vv_wh    = (fptr)d_in[17];
  fptr vv_ws_w  = (fptr)d_in[18];
  fptr vv_ws_b  = (fptr)d_in[19];
  fptr vv_wv    = (fptr)d_in[20];
  fptr vv_wsv_w = (fptr)d_in[21];
  fptr vv_wsv_b = (fptr)d_in[22];
  fptr attn_wh  = (fptr)d_in[23];
  fptr attn_ws_w= (fptr)d_in[24];
  fptr attn_ws_b= (fptr)d_in[25];

  float* ws   = (float*)d_ws;
  float* pexp = ws + OFF_LG;
  float* eqh  = ws + OFF_EQH;
  float* sg   = ws + OFF_SG;
  float* tkh  = ws + OFF_TKH;
  float* tek  = ws + OFF_TEK;
  float* tvs  = ws + OFF_TVS;
  float* tvv  = ws + OFF_TVV;

  kA<<<NC_/ROWS_, 256, 0, stream>>>(s, v, wp_wh, wp_ws_w, wp_ws_b,
                                    q_wh, q_ws_w, q_ws_b, q_wv, q_wsv_w, q_wsv_b,
                                    attn_wh, attn_ws_w, pexp, eqh, sg);
  kAccum<<<800, 256, 0, stream>>>(pexp, s, v, sg);
  kSmall<<<64, 256, 0, stream>>>(sg,
                                 k_wh, k_ws_w, k_ws_b, k_wv, k_wsv_w, k_wsv_b,
                                 vv_wh, vv_ws_w, vv_ws_b, vv_wv, vv_wsv_w, vv_wsv_b,
                                 attn_wh, attn_ws_w, tkh, tek, tvs, tvv);
  kAttn<<<((NC_ + 63)/64)*4, 256, 0, stream>>>(eqh, tkh, tek, tvs, tvv,
                                               attn_ws_w, attn_ws_b, (float*)d_out);
}